// Round 1
// baseline (467.406 us; speedup 1.0000x reference)
//
#include <hip/hip_runtime.h>
#include <math.h>

#define NN 50000
#define NE 800000

// ---------------------------------------------------------------------------
// helpers
// ---------------------------------------------------------------------------
__device__ __forceinline__ void fma4(float4& acc, float s, const float4& w) {
  acc.x = fmaf(s, w.x, acc.x);
  acc.y = fmaf(s, w.y, acc.y);
  acc.z = fmaf(s, w.z, acc.z);
  acc.w = fmaf(s, w.w, acc.w);
}

__device__ __forceinline__ float gate_blend(float v, float hp, float cx) {
  float g = 1.0f / (1.0f + __expf(-v));
  return cx + g * (hp - cx);
}

// ---------------------------------------------------------------------------
// GEMM: out[nrows x 128] = A[nrows x 128] @ W[128 x 128]  (+ mode epilogue)
// MODE 0: out=feat, fused el/er = per-head dot with attn_l/attn_r
// MODE 1: out = A@W + bias
// MODE 2: out = A@W
// MODE 3: gate epilogue: v = A@W + ex1 + bias; g=sigmoid(v);
//         out = g*ex2 + (1-g)*A    (A = conversation_context)
// Tile: 32 rows/block, 256 threads, thread = 4 rows x 4 cols register tile.
// LDS: W 64KB + A-tile 16KB = 80KB dynamic -> 2 blocks/CU.
// ---------------------------------------------------------------------------
template<int MODE>
__global__ __launch_bounds__(256) void gemm_k(
    const float* __restrict__ A, const float* __restrict__ W,
    const float* __restrict__ bias, const float* __restrict__ ex1,
    const float* __restrict__ ex2, const float* __restrict__ al,
    const float* __restrict__ ar, float* __restrict__ elp,
    float* __restrict__ erp, float* __restrict__ out, int nrows)
{
  extern __shared__ float lds[];
  float* Ws = lds;            // [128][128]
  float* As = lds + 128*128;  // [32][128]
  const int tid  = threadIdx.x;
  const int row0 = blockIdx.x * 32;

  // stage W (row-major, float4-coalesced, conflict-free)
  {
    const float4* Wg = (const float4*)W;
    float4* Ws4 = (float4*)Ws;
#pragma unroll
    for (int i = 0; i < 16; i++) Ws4[tid + 256*i] = Wg[tid + 256*i];
  }
  // stage A tile row-major (zero-fill rows past nrows)
  {
    const float4* Ag = (const float4*)A;
    float4* As4 = (float4*)As;
#pragma unroll
    for (int i = 0; i < 4; i++) {
      int idx = tid + 256*i;
      int r = idx >> 5, c4 = idx & 31;
      float4 v = make_float4(0.f, 0.f, 0.f, 0.f);
      if (row0 + r < nrows) v = Ag[(size_t)(row0 + r)*32 + c4];
      As4[idx] = v;
    }
  }
  __syncthreads();

  const int cg = tid & 31;   // 4 cols: 4*cg .. 4*cg+3
  const int rg = tid >> 5;   // 4 rows: rg*4 .. rg*4+3
  float4 acc[4] = {};

  const float4* Ws4 = (const float4*)Ws;
  const float4* As4 = (const float4*)As;
#pragma unroll 4
  for (int k4 = 0; k4 < 32; k4++) {
    float4 w0 = Ws4[(4*k4 + 0)*32 + cg];
    float4 w1 = Ws4[(4*k4 + 1)*32 + cg];
    float4 w2 = Ws4[(4*k4 + 2)*32 + cg];
    float4 w3 = Ws4[(4*k4 + 3)*32 + cg];
#pragma unroll
    for (int i = 0; i < 4; i++) {
      float4 a = As4[(rg*4 + i)*32 + k4];   // broadcast read (2 addrs/wave)
      fma4(acc[i], a.x, w0);
      fma4(acc[i], a.y, w1);
      fma4(acc[i], a.z, w2);
      fma4(acc[i], a.w, w3);
    }
  }

  if (MODE == 0) {
    const float4 alv = ((const float4*)al)[cg];
    const float4 arv = ((const float4*)ar)[cg];
#pragma unroll
    for (int i = 0; i < 4; i++) {
      int row = row0 + rg*4 + i;
      float pl = acc[i].x*alv.x + acc[i].y*alv.y + acc[i].z*alv.z + acc[i].w*alv.w;
      float pr = acc[i].x*arv.x + acc[i].y*arv.y + acc[i].z*arv.z + acc[i].w*arv.w;
#pragma unroll
      for (int m = 1; m < 8; m <<= 1) {   // reduce the 8 col-groups of a head
        pl += __shfl_xor(pl, m);
        pr += __shfl_xor(pr, m);
      }
      if (row < nrows) {
        ((float4*)out)[(size_t)row*32 + cg] = acc[i];
        if ((cg & 7) == 0) {
          int hd = cg >> 3;
          elp[row*4 + hd] = pl;
          erp[row*4 + hd] = pr;
        }
      }
    }
  } else if (MODE == 1) {
    const float4 bv = ((const float4*)bias)[cg];
#pragma unroll
    for (int i = 0; i < 4; i++) {
      int row = row0 + rg*4 + i;
      if (row < nrows) {
        float4 o = acc[i];
        o.x += bv.x; o.y += bv.y; o.z += bv.z; o.w += bv.w;
        ((float4*)out)[(size_t)row*32 + cg] = o;
      }
    }
  } else if (MODE == 2) {
#pragma unroll
    for (int i = 0; i < 4; i++) {
      int row = row0 + rg*4 + i;
      if (row < nrows) ((float4*)out)[(size_t)row*32 + cg] = acc[i];
    }
  } else {
    const float4 bv = ((const float4*)bias)[cg];
#pragma unroll
    for (int i = 0; i < 4; i++) {
      int row = row0 + rg*4 + i;
      if (row < nrows) {
        float4 t4  = ((const float4*)ex1)[(size_t)row*32 + cg];
        float4 hp4 = ((const float4*)ex2)[(size_t)row*32 + cg];
        float4 cx4 = As4[(rg*4 + i)*32 + cg];  // ctx tile already in LDS
        float4 o;
        o.x = gate_blend(acc[i].x + t4.x + bv.x, hp4.x, cx4.x);
        o.y = gate_blend(acc[i].y + t4.y + bv.y, hp4.y, cx4.y);
        o.z = gate_blend(acc[i].z + t4.z + bv.z, hp4.z, cx4.z);
        o.w = gate_blend(acc[i].w + t4.w + bv.w, hp4.w, cx4.w);
        ((float4*)out)[(size_t)row*32 + cg] = o;
      }
    }
  }
}

// ---------------------------------------------------------------------------
// CSR build: histogram -> scan -> scatter
// ---------------------------------------------------------------------------
__global__ __launch_bounds__(256) void hist_k(const int* __restrict__ dst,
                                              int* __restrict__ deg) {
  int e = blockIdx.x*256 + threadIdx.x;
  if (e < NE) atomicAdd(&deg[dst[e]], 1);
}

// single-block exclusive scan of deg[0..NN) -> row_off, cursor
__global__ __launch_bounds__(1024) void scan_k(const int* __restrict__ deg,
                                               int* __restrict__ row_off,
                                               int* __restrict__ cursor) {
  __shared__ int wsum[16];
  __shared__ int s_carry;
  const int tid = threadIdx.x;
  const int ln = tid & 63, wv = tid >> 6;
  if (tid == 0) s_carry = 0;
  __syncthreads();
  for (int base = 0; base < NN; base += 1024) {
    int i = base + tid;
    int x = (i < NN) ? deg[i] : 0;
    int v = x;
#pragma unroll
    for (int d = 1; d < 64; d <<= 1) {
      int t = __shfl_up(v, d);
      if (ln >= d) v += t;
    }
    if (ln == 63) wsum[wv] = v;
    __syncthreads();
    if (tid < 16) {
      int w = wsum[tid];
#pragma unroll
      for (int d = 1; d < 16; d <<= 1) {
        int t = __shfl_up(w, d);
        if (tid >= d) w += t;
      }
      wsum[tid] = w;   // inclusive scan of wave sums
    }
    __syncthreads();
    int waveoff = s_carry + (wv > 0 ? wsum[wv-1] : 0);
    int excl = waveoff + (v - x);
    if (i < NN) { row_off[i] = excl; cursor[i] = excl; }
    int tot = wsum[15];
    __syncthreads();
    if (tid == 0) s_carry += tot;
    __syncthreads();
  }
}

__global__ __launch_bounds__(256) void scatter_k(const int* __restrict__ src,
                                                 const int* __restrict__ dst,
                                                 int* __restrict__ cursor,
                                                 int* __restrict__ ssrc) {
  int e = blockIdx.x*256 + threadIdx.x;
  if (e < NE) {
    int d = dst[e];
    int pos = atomicAdd(&cursor[d], 1);
    ssrc[pos] = src[e];
  }
}

// ---------------------------------------------------------------------------
// Aggregation: one wave per dst node. lane covers feature pair (2*ln, 2*ln+1),
// head = ln>>4. rst = (sum a*feat[src]) / (sum a); +bias; elu -> h_gat.
// ---------------------------------------------------------------------------
__global__ __launch_bounds__(256) void agg_k(
    const float* __restrict__ feat, const float* __restrict__ el,
    const float* __restrict__ er, const int* __restrict__ deg,
    const int* __restrict__ row_off, const int* __restrict__ ssrc,
    const float* __restrict__ bias, float* __restrict__ hgat)
{
  const int wid = (blockIdx.x*256 + threadIdx.x) >> 6;
  if (wid >= NN) return;
  const int ln = threadIdx.x & 63;
  const int head = ln >> 4;
  const int cnt = deg[wid];
  const int start = row_off[wid];
  const float erh = er[wid*4 + head];
  const float2* feat2 = (const float2*)feat;

  float ax = 0.f, ay = 0.f, dn = 0.f;
  for (int base = 0; base < cnt; base += 64) {
    int m = min(64, cnt - base);
    int sv = 0;
    if (ln < m) sv = ssrc[start + base + ln];
    for (int i = 0; i < m; i++) {
      int s = __shfl(sv, i);
      float ev = el[s*4 + head] + erh;
      ev = ev > 0.f ? ev : 0.2f * ev;       // leaky_relu
      float a = __expf(ev);
      float2 f = feat2[(size_t)s*64 + ln];
      ax = fmaf(a, f.x, ax);
      ay = fmaf(a, f.y, ay);
      dn += a;
    }
  }
  float inv = (cnt > 0) ? (1.0f / dn) : 0.0f;
  float rx = ax*inv + bias[2*ln];
  float ry = ay*inv + bias[2*ln + 1];
  rx = rx > 0.f ? rx : expm1f(rx);          // elu
  ry = ry > 0.f ? ry : expm1f(ry);
  float2 o; o.x = rx; o.y = ry;
  ((float2*)hgat)[(size_t)wid*64 + ln] = o;
}

// ---------------------------------------------------------------------------
extern "C" void kernel_launch(void* const* d_in, const int* in_sizes, int n_in,
                              void* d_out, int out_size, void* d_ws, size_t ws_size,
                              hipStream_t stream) {
  const float* h        = (const float*)d_in[0];
  const int*   src      = (const int*)d_in[1];
  const int*   dst      = (const int*)d_in[2];
  const float* ctx      = (const float*)d_in[3];
  const float* W_fc     = (const float*)d_in[4];
  const float* attn_l   = (const float*)d_in[5];
  const float* attn_r   = (const float*)d_in[6];
  const float* bias_gat = (const float*)d_in[7];
  const float* W_proj   = (const float*)d_in[8];
  const float* b_proj   = (const float*)d_in[9];
  const float* W_gate   = (const float*)d_in[10];
  const float* b_gate   = (const float*)d_in[11];
  float* out = (float*)d_out;

  char* ws = (char*)d_ws;
  size_t off = 0;
  auto take = [&](size_t bytes) -> void* {
    void* p = ws + off;
    off += (bytes + 255) & ~(size_t)255;
    return p;
  };
  float* feat    = (float*)take((size_t)NN*128*4);
  float* hgat    = (float*)take((size_t)NN*128*4);
  float* el      = (float*)take((size_t)NN*4*4);
  float* er      = (float*)take((size_t)NN*4*4);
  int*   deg     = (int*)take((size_t)NN*4);
  int*   row_off = (int*)take((size_t)NN*4);
  int*   cursor  = (int*)take((size_t)NN*4);
  int*   ssrc    = (int*)take((size_t)NE*4);
  float* hproj = feat;   // reuse: feat dead after aggregation
  float* tbuf  = hgat;   // reuse: h_gat dead after proj GEMM

  hipMemsetAsync(deg, 0, (size_t)NN*4, stream);

  const size_t smem = (128*128 + 32*128) * sizeof(float);  // 80 KB
  const int gb = (NN + 31) / 32;
  const int eb = (NE + 255) / 256;

  // 1. feat = h @ W_fc  (+ el/er)
  gemm_k<0><<<gb, 256, smem, stream>>>(h, W_fc, nullptr, nullptr, nullptr,
                                       attn_l, attn_r, el, er, feat, NN);
  // 2. CSR build
  hist_k<<<eb, 256, 0, stream>>>(dst, deg);
  scan_k<<<1, 1024, 0, stream>>>(deg, row_off, cursor);
  scatter_k<<<eb, 256, 0, stream>>>(src, dst, cursor, ssrc);
  // 3. edge-softmax aggregation -> h_gat
  agg_k<<<NN/4, 256, 0, stream>>>(feat, el, er, deg, row_off, ssrc, bias_gat, hgat);
  // 4. h_proj = h_gat @ W_proj + b_proj
  gemm_k<1><<<gb, 256, smem, stream>>>(hgat, W_proj, b_proj, nullptr, nullptr,
                                       nullptr, nullptr, nullptr, nullptr, hproj, NN);
  // 5. t = h_proj @ W_gate[0:128,:]
  gemm_k<2><<<gb, 256, smem, stream>>>(hproj, W_gate, nullptr, nullptr, nullptr,
                                       nullptr, nullptr, nullptr, nullptr, tbuf, NN);
  // 6. g = sigmoid(ctx @ W_gate[128:256,:] + t + b_gate); out = g*hproj+(1-g)*ctx
  gemm_k<3><<<gb, 256, smem, stream>>>(ctx, W_gate + 128*128, b_gate, tbuf, hproj,
                                       nullptr, nullptr, nullptr, nullptr, out, NN);
}

// Round 2
// 300.003 us; speedup vs baseline: 1.5580x; 1.5580x over previous
//
#include <hip/hip_runtime.h>
#include <math.h>

#define NN 50000
#define NE 800000
#define NB 196   // (NN+255)/256

typedef __bf16 bf16x8 __attribute__((ext_vector_type(8)));
typedef float  f32x4  __attribute__((ext_vector_type(4)));

__device__ __forceinline__ ushort f2b(float f) {
  union { float f; uint u; } v; v.f = f;
  uint u = v.u;
  return (ushort)((u + 0x7fffu + ((u >> 16) & 1u)) >> 16);  // RNE
}
__device__ __forceinline__ float b2f(ushort b) {
  union { uint u; float f; } v; v.u = ((uint)b) << 16;
  return v.f;
}

// ---------------------------------------------------------------------------
// cvt_vec: h, ctx f32 -> bf16 (4 elems/thread). grid*256*4 == 2*NN*128 exactly.
// ---------------------------------------------------------------------------
__global__ __launch_bounds__(256) void cvt_vec(const float* __restrict__ h,
    const float* __restrict__ ctx, ushort* __restrict__ hb,
    ushort* __restrict__ ctxb) {
  const int NF4 = NN * 128 / 4;
  int t = blockIdx.x * 256 + threadIdx.x;
  const float4* s; ushort* d; int i;
  if (t < NF4) { s = (const float4*)h;   d = hb;   i = t; }
  else         { s = (const float4*)ctx; d = ctxb; i = t - NF4; }
  float4 v = s[i];
  ushort4 o; o.x = f2b(v.x); o.y = f2b(v.y); o.z = f2b(v.z); o.w = f2b(v.w);
  *(ushort4*)(d + (size_t)i * 4) = o;
}

// ---------------------------------------------------------------------------
// cvt_w: weights -> bf16, transposed to [n][k] so B-fragments are k-contiguous
// ---------------------------------------------------------------------------
__global__ __launch_bounds__(256) void cvt_w(const float* __restrict__ Wfc,
    const float* __restrict__ Wpr, const float* __restrict__ Wgt,
    ushort* __restrict__ Tfc, ushort* __restrict__ Tpr, ushort* __restrict__ Tgt) {
  int t = blockIdx.x * 256 + threadIdx.x;
  if (t < 16384) {
    int n = t >> 7, k = t & 127;
    Tfc[n * 128 + k] = f2b(Wfc[k * 128 + n]);
  } else if (t < 32768) {
    int i = t - 16384; int n = i >> 7, k = i & 127;
    Tpr[n * 128 + k] = f2b(Wpr[k * 128 + n]);
  } else if (t < 65536) {
    int i = t - 32768; int n = i >> 8, k = i & 255;
    Tgt[n * 256 + k] = f2b(Wgt[k * 128 + n]);
  }
}

// ---------------------------------------------------------------------------
// MFMA GEMM: out[M x 128] = A[M x K] @ W[K x 128], K = KS*32 (128 or 256).
// A0/A1: bf16 row-major [M][128] (A1 = second K-half for MODE 2).
// Wt: bf16 [128 n][K k] (pre-transposed).
// Block: 128 rows, 256 thr = 4 waves (2x2), wave = 64x64 via 4x4 16x16 frags.
// LDS: A-tile + B-tile, XOR-swizzled 16B units: byte ^= (row&7)<<4 (G4 fix).
// MODE 0: store bf16. MODE 1: +bias[col], store bf16.
// MODE 2: v=acc+bias; g=sigmoid(v); out_f32 = g*hp + (1-g)*ctx, hp/ctx read
//         back from the LDS A-tile (k=col and k=128+col).
// ---------------------------------------------------------------------------
template<int KS, int MODE>
__global__ __launch_bounds__(256) void mgemm(
    const ushort* __restrict__ A0, const ushort* __restrict__ A1,
    const ushort* __restrict__ Wt, const float* __restrict__ bias,
    ushort* __restrict__ outb, float* __restrict__ outf, int M)
{
  constexpr int K  = KS * 32;
  constexpr int K2 = K * 2;              // bytes per LDS row
  constexpr int CPR = K2 / 16;           // 16B chunks per row
  constexpr int CHT = 128 * CPR / 256;   // chunks per thread per tile
  extern __shared__ char lds[];
  char* As = lds;
  char* Bs = lds + 128 * K2;
  const int tid  = threadIdx.x;
  const int row0 = blockIdx.x * 128;

  const float4 zz = make_float4(0.f, 0.f, 0.f, 0.f);
#pragma unroll
  for (int c = 0; c < CHT; c++) {
    int idx = tid + c * 256;
    int r  = idx / CPR;
    int kc = idx % CPR;
    int sw = ((kc * 16) ^ ((r & 7) << 4));
    // A-tile
    float4 va = zz;
    int grow = row0 + r;
    if (grow < M) {
      if (MODE == 2) {
        va = (kc < CPR / 2)
               ? *(const float4*)(A0 + (size_t)grow * 128 + kc * 8)
               : *(const float4*)(A1 + (size_t)grow * 128 + (kc - CPR / 2) * 8);
      } else {
        va = *(const float4*)(A0 + (size_t)grow * 128 + kc * 8);
      }
    }
    *(float4*)(As + r * K2 + sw) = va;
    // B-tile (Wt is linear [128][K])
    float4 vb = *(const float4*)(Wt + (size_t)idx * 8);
    *(float4*)(Bs + r * K2 + sw) = vb;
  }
  __syncthreads();

  const int ln = tid & 63, wv = tid >> 6;
  const int wm = wv >> 1, wn = wv & 1;
  const int lr = ln & 15, lk = ln >> 4;

  f32x4 acc[4][4] = {};
#pragma unroll
  for (int ks = 0; ks < KS; ks++) {
    int k2 = ks * 64 + lk * 16;
    bf16x8 af[4], bfr[4];
#pragma unroll
    for (int t = 0; t < 4; t++) {
      int ar = wm * 64 + t * 16 + lr;
      af[t]  = *(const bf16x8*)(As + ar * K2 + (k2 ^ ((ar & 7) << 4)));
      int bn = wn * 64 + t * 16 + lr;
      bfr[t] = *(const bf16x8*)(Bs + bn * K2 + (k2 ^ ((bn & 7) << 4)));
    }
#pragma unroll
    for (int mt = 0; mt < 4; mt++)
#pragma unroll
      for (int nt = 0; nt < 4; nt++)
        acc[mt][nt] = __builtin_amdgcn_mfma_f32_16x16x32_bf16(
            af[mt], bfr[nt], acc[mt][nt], 0, 0, 0);
  }

#pragma unroll
  for (int mt = 0; mt < 4; mt++) {
    int rbase = wm * 64 + mt * 16 + lk * 4;
#pragma unroll
    for (int r = 0; r < 4; r++) {
      int lrow = rbase + r;
      int row  = row0 + lrow;
      if (row >= M) continue;
#pragma unroll
      for (int nt = 0; nt < 4; nt++) {
        int col = wn * 64 + nt * 16 + lr;
        float v = acc[mt][nt][r];
        if (MODE == 0) {
          outb[(size_t)row * 128 + col] = f2b(v);
        } else if (MODE == 1) {
          outb[(size_t)row * 128 + col] = f2b(v + bias[col]);
        } else {
          float hp = b2f(*(const ushort*)(As + lrow * K2 +
                          ((2 * col) ^ ((lrow & 7) << 4))));
          float cx = b2f(*(const ushort*)(As + lrow * K2 +
                          ((2 * col + 256) ^ ((lrow & 7) << 4))));
          float g = 1.f / (1.f + __expf(-(v + bias[col])));
          outf[(size_t)row * 128 + col] = cx + g * (hp - cx);
        }
      }
    }
  }
}

// ---------------------------------------------------------------------------
// el/er: one wave per node; lane covers features (2l, 2l+1); head = l>>4.
// ---------------------------------------------------------------------------
__global__ __launch_bounds__(256) void elr_k(const ushort* __restrict__ featb,
    const float* __restrict__ al, const float* __restrict__ ar,
    float* __restrict__ el, float* __restrict__ er)
{
  const int wid = (blockIdx.x * 256 + threadIdx.x) >> 6;
  if (wid >= NN) return;
  const int ln = threadIdx.x & 63;
  const int head = ln >> 4;
  uint u = ((const uint*)featb)[(size_t)wid * 64 + ln];
  float f0 = b2f((ushort)(u & 0xffff)), f1 = b2f((ushort)(u >> 16));
  int d0 = 2 * (ln & 15);
  float pl = f0 * al[head * 32 + d0] + f1 * al[head * 32 + d0 + 1];
  float pr = f0 * ar[head * 32 + d0] + f1 * ar[head * 32 + d0 + 1];
#pragma unroll
  for (int m2 = 1; m2 < 16; m2 <<= 1) {
    pl += __shfl_xor(pl, m2);
    pr += __shfl_xor(pr, m2);
  }
  if ((ln & 15) == 0) {
    el[wid * 4 + head] = pl;
    er[wid * 4 + head] = pr;
  }
}

// ---------------------------------------------------------------------------
// CSR build
// ---------------------------------------------------------------------------
__global__ __launch_bounds__(256) void hist_k(const int* __restrict__ dst,
                                              int* __restrict__ deg) {
  int e = blockIdx.x * 256 + threadIdx.x;
  if (e < NE) atomicAdd(&deg[dst[e]], 1);
}

__device__ __forceinline__ int block_scan_excl(int x, int* tot) {
  __shared__ int ws[4];
  int tid = threadIdx.x, ln = tid & 63, wv = tid >> 6;
  int v = x;
#pragma unroll
  for (int d = 1; d < 64; d <<= 1) {
    int t = __shfl_up(v, d);
    if (ln >= d) v += t;
  }
  if (ln == 63) ws[wv] = v;
  __syncthreads();
  int w0 = ws[0], w1 = ws[1], w2 = ws[2], w3 = ws[3];
  int woff = (wv == 0) ? 0 : (wv == 1) ? w0 : (wv == 2) ? w0 + w1 : w0 + w1 + w2;
  *tot = w0 + w1 + w2 + w3;
  return woff + v - x;
}

__global__ __launch_bounds__(256) void scan1(const int* __restrict__ deg,
                                             int* __restrict__ bsum) {
  int i = blockIdx.x * 256 + threadIdx.x;
  int x = (i < NN) ? deg[i] : 0;
  int tot;
  block_scan_excl(x, &tot);
  if (threadIdx.x == 0) bsum[blockIdx.x] = tot;
}

__global__ __launch_bounds__(256) void scan2(const int* __restrict__ bsum,
                                             int* __restrict__ boff) {
  int x = (threadIdx.x < NB) ? bsum[threadIdx.x] : 0;
  int tot;
  int e = block_scan_excl(x, &tot);
  if (threadIdx.x < NB) boff[threadIdx.x] = e;
}

__global__ __launch_bounds__(256) void scan3(const int* __restrict__ deg,
                                             const int* __restrict__ boff,
                                             int* __restrict__ row_off,
                                             int* __restrict__ cursor) {
  int i = blockIdx.x * 256 + threadIdx.x;
  int x = (i < NN) ? deg[i] : 0;
  int tot;
  int e = block_scan_excl(x, &tot) + boff[blockIdx.x];
  if (i < NN) { row_off[i] = e; cursor[i] = e; }
}

__global__ __launch_bounds__(256) void scatter_k(const int* __restrict__ src,
                                                 const int* __restrict__ dst,
                                                 int* __restrict__ cursor,
                                                 int* __restrict__ ssrc) {
  int e = blockIdx.x * 256 + threadIdx.x;
  if (e < NE) {
    int d = dst[e];
    int pos = atomicAdd(&cursor[d], 1);
    ssrc[pos] = src[e];
  }
}

// ---------------------------------------------------------------------------
// Aggregation: one wave per dst node; lane covers features (2l,2l+1) bf16.
// rst = (sum a*feat[src]) / (sum a); +bias; elu -> h_gat (bf16).
// 2-way edge unroll for gather-latency ILP.
// ---------------------------------------------------------------------------
__global__ __launch_bounds__(256) void agg_k(
    const ushort* __restrict__ featb, const float* __restrict__ el,
    const float* __restrict__ er, const int* __restrict__ deg,
    const int* __restrict__ row_off, const int* __restrict__ ssrc,
    const float* __restrict__ bias, ushort* __restrict__ hgatb)
{
  const int wid = (blockIdx.x * 256 + threadIdx.x) >> 6;
  if (wid >= NN) return;
  const int ln = threadIdx.x & 63;
  const int head = ln >> 4;
  const int cnt = deg[wid];
  const int start = row_off[wid];
  const float erh = er[wid * 4 + head];
  const uint* f2 = (const uint*)featb;

  float ax0 = 0.f, ay0 = 0.f, dn0 = 0.f;
  float ax1 = 0.f, ay1 = 0.f, dn1 = 0.f;
  for (int base = 0; base < cnt; base += 64) {
    int m = min(64, cnt - base);
    int sv = (ln < m) ? ssrc[start + base + ln] : 0;
    int i = 0;
    for (; i + 1 < m; i += 2) {
      int s0 = __shfl(sv, i), s1 = __shfl(sv, i + 1);
      float e0 = el[s0 * 4 + head] + erh;
      float e1 = el[s1 * 4 + head] + erh;
      uint u0 = f2[(size_t)s0 * 64 + ln];
      uint u1 = f2[(size_t)s1 * 64 + ln];
      e0 = e0 > 0.f ? e0 : 0.2f * e0;
      e1 = e1 > 0.f ? e1 : 0.2f * e1;
      float a0 = __expf(e0), a1 = __expf(e1);
      ax0 = fmaf(a0, b2f((ushort)(u0 & 0xffff)), ax0);
      ay0 = fmaf(a0, b2f((ushort)(u0 >> 16)), ay0);
      dn0 += a0;
      ax1 = fmaf(a1, b2f((ushort)(u1 & 0xffff)), ax1);
      ay1 = fmaf(a1, b2f((ushort)(u1 >> 16)), ay1);
      dn1 += a1;
    }
    if (i < m) {
      int s0 = __shfl(sv, i);
      float e0 = el[s0 * 4 + head] + erh;
      uint u0 = f2[(size_t)s0 * 64 + ln];
      e0 = e0 > 0.f ? e0 : 0.2f * e0;
      float a0 = __expf(e0);
      ax0 = fmaf(a0, b2f((ushort)(u0 & 0xffff)), ax0);
      ay0 = fmaf(a0, b2f((ushort)(u0 >> 16)), ay0);
      dn0 += a0;
    }
  }
  float dn = dn0 + dn1;
  float inv = (cnt > 0) ? (1.0f / dn) : 0.0f;
  float2 bv = ((const float2*)bias)[ln];
  float rx = fmaf(ax0 + ax1, inv, bv.x);
  float ry = fmaf(ay0 + ay1, inv, bv.y);
  rx = rx > 0.f ? rx : expm1f(rx);
  ry = ry > 0.f ? ry : expm1f(ry);
  uint o = (uint)f2b(rx) | ((uint)f2b(ry) << 16);
  ((uint*)hgatb)[(size_t)wid * 64 + ln] = o;
}

// ---------------------------------------------------------------------------
extern "C" void kernel_launch(void* const* d_in, const int* in_sizes, int n_in,
                              void* d_out, int out_size, void* d_ws, size_t ws_size,
                              hipStream_t stream) {
  const float* h        = (const float*)d_in[0];
  const int*   src      = (const int*)d_in[1];
  const int*   dst      = (const int*)d_in[2];
  const float* ctx      = (const float*)d_in[3];
  const float* W_fc     = (const float*)d_in[4];
  const float* attn_l   = (const float*)d_in[5];
  const float* attn_r   = (const float*)d_in[6];
  const float* bias_gat = (const float*)d_in[7];
  const float* W_proj   = (const float*)d_in[8];
  const float* b_proj   = (const float*)d_in[9];
  const float* W_gate   = (const float*)d_in[10];
  const float* b_gate   = (const float*)d_in[11];
  float* out = (float*)d_out;

  char* ws = (char*)d_ws;
  size_t off = 0;
  auto take = [&](size_t bytes) -> void* {
    void* p = ws + off;
    off += (bytes + 255) & ~(size_t)255;
    return p;
  };
  ushort* featb  = (ushort*)take((size_t)NN * 128 * 2);
  ushort* hgatb  = (ushort*)take((size_t)NN * 128 * 2);
  ushort* hb     = (ushort*)take((size_t)NN * 128 * 2);   // -> reused as hpb
  ushort* ctxb   = (ushort*)take((size_t)NN * 128 * 2);
  float*  el     = (float*)take((size_t)NN * 4 * 4);
  float*  er     = (float*)take((size_t)NN * 4 * 4);
  int*    deg    = (int*)take((size_t)NN * 4);
  int*    row_off= (int*)take((size_t)NN * 4);
  int*    cursor = (int*)take((size_t)NN * 4);
  int*    bsum   = (int*)take((size_t)NB * 4);
  int*    boff   = (int*)take((size_t)NB * 4);
  int*    ssrc   = (int*)take((size_t)NE * 4);
  ushort* Tfc    = (ushort*)take(16384 * 2);
  ushort* Tpr    = (ushort*)take(16384 * 2);
  ushort* Tgt    = (ushort*)take(32768 * 2);
  ushort* hpb = hb;  // hb dead after mgemm<4,0>

  hipMemsetAsync(deg, 0, (size_t)NN * 4, stream);

  const int gb = (NN + 127) / 128;       // 391
  const int eb = (NE + 255) / 256;       // 3125
  const size_t smem4 = 2 * 128 * 256;    // 64 KB  (KS=4)
  const size_t smem8 = 2 * 128 * 512;    // 128 KB (KS=8)

  cvt_vec<<<12500, 256, 0, stream>>>(h, ctx, hb, ctxb);
  cvt_w<<<256, 256, 0, stream>>>(W_fc, W_proj, W_gate, Tfc, Tpr, Tgt);

  // 1. feat = h @ W_fc (bf16 out)
  mgemm<4, 0><<<gb, 256, smem4, stream>>>(hb, nullptr, Tfc, nullptr,
                                          featb, nullptr, NN);
  // 2. el/er
  elr_k<<<12500, 256, 0, stream>>>(featb, attn_l, attn_r, el, er);
  // 3. CSR build
  hist_k<<<eb, 256, 0, stream>>>(dst, deg);
  scan1<<<NB, 256, 0, stream>>>(deg, bsum);
  scan2<<<1, 256, 0, stream>>>(bsum, boff);
  scan3<<<NB, 256, 0, stream>>>(deg, boff, row_off, cursor);
  scatter_k<<<eb, 256, 0, stream>>>(src, dst, cursor, ssrc);
  // 4. edge-softmax aggregation -> h_gat (bf16)
  agg_k<<<12500, 256, 0, stream>>>(featb, el, er, deg, row_off, ssrc,
                                   bias_gat, hgatb);
  // 5. h_proj = h_gat @ W_proj + b_proj (bf16 out)
  mgemm<4, 1><<<gb, 256, smem4, stream>>>(hgatb, nullptr, Tpr, b_proj,
                                          hpb, nullptr, NN);
  // 6. fused gate GEMM (K=256): g = sigmoid([hp,ctx]@W_gate + b_gate);
  //    out = g*hp + (1-g)*ctx
  mgemm<8, 2><<<gb, 256, smem8, stream>>>(hpb, ctxb, Tgt, b_gate,
                                          nullptr, out, NN);
}